// Round 3
// baseline (227.812 us; speedup 1.0000x reference)
//
#include <hip/hip_runtime.h>
#include <math.h>

// TaskAdaptiveRouter: logits = x @ Wr[:, :2048]^T + task_logits; softmax; top2; aux.
// B=4, L=4096 -> 16384 tokens; D=2048; DT=16; E=64; K=2; TEMP=1.
//
// d_out (f32): [0,32768) topw ; [32768,65536) topi(float) ; [65536,1114112) probs ;
//              [1114112] aux.
// d_ws  (f32): [0,256) task logits tl[4][64] ; [256,1280) P/F slots [8][{P:64,F:64}].
//
// k2: grid 256 token-groups(64) x block 512thr (8 waves). Wave w: 64 tokens (lane=token)
// x 8 experts (e0=8w). x via global_load_lds triple-buffer (counted vmcnt + raw barrier);
// W via wave-uniform s_load_dwordx4 -> SGPR FMA operand (no LDS for W). Epilogue:
// cross-wave logit exchange in LDS, per-row softmax/top2, P/f block-reduce, 8-slot atomics.

#define DDIM 2048
#define WROW 2064

typedef unsigned int u32;
typedef const __attribute__((address_space(1))) u32* gp1;
typedef __attribute__((address_space(3))) u32* lp3;

// ---------------- kernel 1: task proj + task logits + zero P/F slots -------------
__global__ void k1_task(const float* __restrict__ z, const float* __restrict__ Wp,
                        const float* __restrict__ bp, const float* __restrict__ Wr,
                        const float* __restrict__ eb, float* __restrict__ wsb) {
    __shared__ float tp[4][16];
    const int t = threadIdx.x;
    if (t < 64) {
        const int b = t >> 4, r = t & 15;
        float s = bp[r];
        #pragma unroll
        for (int i = 0; i < 16; ++i) s += z[b * 16 + i] * Wp[r * 16 + i];
        tp[b][r] = 0.5f * s * (1.0f + erff(s * 0.70710678118654752440f));
    }
    #pragma unroll
    for (int i = t; i < 1024; i += 256) wsb[256 + i] = 0.0f;   // zero 8 P/F slots
    __syncthreads();
    {
        const int b = t >> 6, e = t & 63;
        const float* wr = Wr + (size_t)e * WROW + DDIM;
        float s = eb[e];
        #pragma unroll
        for (int i = 0; i < 16; ++i) s += tp[b][i] * wr[i];
        wsb[b * 64 + e] = s;
    }
}

// ---------------- kernel 2: fused logits + softmax + top2 + probs + P/f ----------
__global__ __launch_bounds__(512, 2) void k2_fused(const float* __restrict__ x,
                                                   const float* __restrict__ Wr,
                                                   float* __restrict__ wsb,
                                                   float* __restrict__ out) {
    __shared__ __align__(16) float xbuf[3 * 2048];   // triple-buffered x tiles (24 KB)
    __shared__ __align__(16) float lg[64 * 68];      // logit exchange, pad 68 (17 KB)
    __shared__ __align__(16) float pf[8 * 128];      // P/f partials (4 KB)

    const int tid  = threadIdx.x;
    const int wv   = __builtin_amdgcn_readfirstlane(tid >> 6);  // wave 0..7 (scalar)
    const int lane = tid & 63;
    const int tok0 = blockIdx.x * 64;
    const int bb   = tok0 >> 12;            // batch index (uniform)
    const int e0   = wv * 8;                // this wave's experts (scalar)

    // per-lane global src for DMA staging: wave wv stages chunk wv (4 k-values/lane)
    const float* xrow = x + (size_t)(tok0 + lane) * DDIM + wv * 4;
    // scalar W base for this wave's 8 experts
    const float* wb = Wr + (size_t)e0 * WROW;

    float acc[8];
    #pragma unroll
    for (int e = 0; e < 8; ++e) acc[e] = wsb[bb * 64 + e0 + e];  // init = task logits

#define STAGE(t) do {                                                         \
        const float* _s = xrow + (t) * 32;                                    \
        float* _d = &xbuf[((t) % 3) * 2048 + wv * 256];                       \
        __builtin_amdgcn_global_load_lds((gp1)_s, (lp3)_d, 16, 0, 0);         \
    } while (0)

#define COMPUTE(t) do {                                                       \
        const float* _b = &xbuf[((t) % 3) * 2048];                            \
        const float* _w = wb + (t) * 32;                                      \
        _Pragma("unroll")                                                     \
        for (int q = 0; q < 8; ++q) {                                         \
            const float4 xv = *(const float4*)(_b + q * 256 + lane * 4);      \
            _Pragma("unroll")                                                 \
            for (int e = 0; e < 8; ++e) {                                     \
                const float4 wq = *(const float4*)(_w + (size_t)e * WROW + q * 4); \
                acc[e] += xv.x * wq.x;                                        \
                acc[e] += xv.y * wq.y;                                        \
                acc[e] += xv.z * wq.z;                                        \
                acc[e] += xv.w * wq.w;                                        \
            }                                                                 \
        }                                                                     \
    } while (0)

    STAGE(0); STAGE(1);
    for (int t = 0; t < 62; ++t) {
        asm volatile("s_waitcnt vmcnt(1)" ::: "memory");  // my tile-t DMA landed
        __builtin_amdgcn_s_barrier();                     // everyone's tile t ready;
                                                          // everyone done with t-1
        STAGE(t + 2);                                     // overwrite slot (t-1)%3
        COMPUTE(t);
    }
    asm volatile("s_waitcnt vmcnt(1)" ::: "memory");
    __builtin_amdgcn_s_barrier();
    COMPUTE(62);
    asm volatile("s_waitcnt vmcnt(0)" ::: "memory");
    __builtin_amdgcn_s_barrier();
    COMPUTE(63);

    // ---- logit exchange: lane=token writes its 8 experts ----
    #pragma unroll
    for (int e = 0; e < 8; e += 4) {
        float4 v; v.x = acc[e]; v.y = acc[e + 1]; v.z = acc[e + 2]; v.w = acc[e + 3];
        *(float4*)&lg[lane * 68 + e0 + e] = v;
    }
    __syncthreads();

    // ---- softmax/top2 for tokens 8wv..8wv+7 ; lane = expert ----
    float pacc = 0.0f, facc = 0.0f;
    for (int i = 0; i < 8; ++i) {
        const int tk = wv * 8 + i;
        const float v = lg[tk * 68 + lane];
        float m1 = v; int i1 = lane;
        #pragma unroll
        for (int off = 32; off; off >>= 1) {
            const float ov = __shfl_xor(m1, off, 64);
            const int   oi = __shfl_xor(i1, off, 64);
            if (ov > m1 || (ov == m1 && oi < i1)) { m1 = ov; i1 = oi; }
        }
        const float vx = (lane == i1) ? -3.4e38f : v;
        float m2 = vx; int i2 = lane;
        #pragma unroll
        for (int off = 32; off; off >>= 1) {
            const float ov = __shfl_xor(m2, off, 64);
            const int   oi = __shfl_xor(i2, off, 64);
            if (ov > m2 || (ov == m2 && oi < i2)) { m2 = ov; i2 = oi; }
        }
        const float p = __expf(v - m1);
        float s = p;
        #pragma unroll
        for (int off = 32; off; off >>= 1) s += __shfl_xor(s, off, 64);
        const float rZ = 1.0f / s;
        const float pn = p * rZ;
        const int   T  = tok0 + tk;
        out[65536 + (size_t)T * 64 + lane] = pn;      // coalesced 256 B
        pacc += pn;
        facc += (lane == i1 ? 1.0f : 0.0f) + (lane == i2 ? 1.0f : 0.0f);
        if (lane == 0) {
            const float q1 = rZ, q2 = __expf(m2 - m1) * rZ;
            const float dn = 1.0f / (q1 + q2 + 1e-8f);
            float2 tw; tw.x = q1 * dn; tw.y = q2 * dn;
            *(float2*)(out + (size_t)T * 2) = tw;
            float2 ti; ti.x = (float)i1; ti.y = (float)i2;
            *(float2*)(out + 32768 + (size_t)T * 2) = ti;
        }
    }

    // ---- block-level P/f reduce -> one atomic per address per block (8 slots) ----
    pf[wv * 128 + lane]      = pacc;
    pf[wv * 128 + 64 + lane] = facc;
    __syncthreads();
    if (wv == 0) {
        float ps = 0.0f, fs = 0.0f;
        #pragma unroll
        for (int w2 = 0; w2 < 8; ++w2) {
            ps += pf[w2 * 128 + lane];
            fs += pf[w2 * 128 + 64 + lane];
        }
        const int slot = blockIdx.x & 7;
        atomicAdd(wsb + 256 + slot * 128 + lane, ps);
        atomicAdd(wsb + 256 + slot * 128 + 64 + lane, fs);
    }
#undef STAGE
#undef COMPUTE
}

// ---------------- kernel 3: aux loss ----------------------------------------------
__global__ void k3_aux(const float* __restrict__ wsb, float* __restrict__ out) {
    const int e = threadIdx.x;  // 64 threads
    float P = 0.0f, F = 0.0f;
    #pragma unroll
    for (int s = 0; s < 8; ++s) {
        P += wsb[256 + s * 128 + e];
        F += wsb[256 + s * 128 + 64 + e];
    }
    float val = P * F;
    #pragma unroll
    for (int off = 32; off; off >>= 1) val += __shfl_xor(val, off, 64);
    if (e == 0)
        out[1114112] = 64.0f * val / (16384.0f * 2.0f * 16384.0f);
}

extern "C" void kernel_launch(void* const* d_in, const int* in_sizes, int n_in,
                              void* d_out, int out_size, void* d_ws, size_t ws_size,
                              hipStream_t stream) {
    (void)in_sizes; (void)n_in; (void)out_size; (void)ws_size;
    const float* x  = (const float*)d_in[0];
    const float* z  = (const float*)d_in[1];
    const float* Wr = (const float*)d_in[2];
    const float* Wp = (const float*)d_in[3];
    const float* bp = (const float*)d_in[4];
    const float* eb = (const float*)d_in[5];
    float* out = (float*)d_out;
    float* wsb = (float*)d_ws;

    hipLaunchKernelGGL(k1_task,  dim3(1),   dim3(256), 0, stream, z, Wp, bp, Wr, eb, wsb);
    hipLaunchKernelGGL(k2_fused, dim3(256), dim3(512), 0, stream, x, Wr, wsb, out);
    hipLaunchKernelGGL(k3_aux,   dim3(1),   dim3(64),  0, stream, wsb, out);
}

// Round 4
// 177.198 us; speedup vs baseline: 1.2856x; 1.2856x over previous
//
#include <hip/hip_runtime.h>
#include <math.h>

// TaskAdaptiveRouter: logits = x @ Wr[:, :2048]^T + task_logits; softmax; top2; aux.
// B=4, L=4096 -> 16384 tokens; D=2048; DT=16; E=64; K=2; TEMP=1.
//
// d_out (f32): [0,32768) topw ; [32768,65536) topi(float) ; [65536,1114112) probs ;
//              [1114112] aux.
// d_ws  (f32): [0,256) task logits tl[4][64] ; [256,1280) P/F slots [8][{P:64,F:64}].
//
// k2: grid 256 x 512thr (8 waves). Wave wv: 64 tokens (lane=token) x 8 experts.
// x: global_load_lds triple-buffer (counted vmcnt + raw barrier, DMA only -> vmcnt clean).
// W: explicit inline-asm s_load_dwordx4 -> SGPRs, double-buffered 4k-subtiles,
//    lgkmcnt(0) waits bound via tied "+s" operands (SMEM is unordered; rule #18 anti-hoist).

#define DDIM 2048
#define WROW 2064          // W_router row stride (floats); 8256 bytes

typedef unsigned int u32;
typedef const __attribute__((address_space(1))) u32* gp1;
typedef __attribute__((address_space(3))) u32* lp3;
using f32x4 = __attribute__((ext_vector_type(4))) float;

// ---------------- kernel 1: task proj + task logits + zero P/F slots -------------
__global__ void k1_task(const float* __restrict__ z, const float* __restrict__ Wp,
                        const float* __restrict__ bp, const float* __restrict__ Wr,
                        const float* __restrict__ eb, float* __restrict__ wsb) {
    __shared__ float tp[4][16];
    const int t = threadIdx.x;
    if (t < 64) {
        const int b = t >> 4, r = t & 15;
        float s = bp[r];
        #pragma unroll
        for (int i = 0; i < 16; ++i) s += z[b * 16 + i] * Wp[r * 16 + i];
        tp[b][r] = 0.5f * s * (1.0f + erff(s * 0.70710678118654752440f));
    }
    #pragma unroll
    for (int i = t; i < 1024; i += 256) wsb[256 + i] = 0.0f;   // zero 8 P/F slots
    __syncthreads();
    {
        const int b = t >> 6, e = t & 63;
        const float* wr = Wr + (size_t)e * WROW + DDIM;
        float s = eb[e];
        #pragma unroll
        for (int i = 0; i < 16; ++i) s += tp[b][i] * wr[i];
        wsb[b * 64 + e] = s;
    }
}

// ---- W subtile load: 8 experts x 4k -> 32 SGPRs (8x s_load_dwordx4, imm offsets) ----
template <int KOFF>
__device__ __forceinline__ void wload8(f32x4 (&w)[8], const float* base) {
    asm volatile(
        "s_load_dwordx4 %0, %[p], %c[o0]\n\t"
        "s_load_dwordx4 %1, %[p], %c[o1]\n\t"
        "s_load_dwordx4 %2, %[p], %c[o2]\n\t"
        "s_load_dwordx4 %3, %[p], %c[o3]\n\t"
        "s_load_dwordx4 %4, %[p], %c[o4]\n\t"
        "s_load_dwordx4 %5, %[p], %c[o5]\n\t"
        "s_load_dwordx4 %6, %[p], %c[o6]\n\t"
        "s_load_dwordx4 %7, %[p], %c[o7]"
        : "=&s"(w[0]), "=&s"(w[1]), "=&s"(w[2]), "=&s"(w[3]),
          "=&s"(w[4]), "=&s"(w[5]), "=&s"(w[6]), "=&s"(w[7])
        : [p]"s"(base),
          [o0]"i"(KOFF + 0 * 8256), [o1]"i"(KOFF + 1 * 8256),
          [o2]"i"(KOFF + 2 * 8256), [o3]"i"(KOFF + 3 * 8256),
          [o4]"i"(KOFF + 4 * 8256), [o5]"i"(KOFF + 5 * 8256),
          [o6]"i"(KOFF + 6 * 8256), [o7]"i"(KOFF + 7 * 8256));
}

// wait for the s_loads feeding `w`; tied "+s" operands order all later uses after this
__device__ __forceinline__ void wwait(f32x4 (&w)[8]) {
    asm volatile("s_waitcnt lgkmcnt(0)"
        : "+s"(w[0]), "+s"(w[1]), "+s"(w[2]), "+s"(w[3]),
          "+s"(w[4]), "+s"(w[5]), "+s"(w[6]), "+s"(w[7]));
}

// ---------------- kernel 2: fused logits + softmax + top2 + probs + P/f ----------
__global__ __launch_bounds__(512, 2) void k2_fused(const float* __restrict__ x,
                                                   const float* __restrict__ Wr,
                                                   float* __restrict__ wsb,
                                                   float* __restrict__ out) {
    __shared__ __align__(16) float xbuf[3 * 2048];   // triple-buffered x tiles (24 KB)
    __shared__ __align__(16) float lg[64 * 68];      // logit exchange (17 KB)
    __shared__ __align__(16) float pf[8 * 128];      // P/f partials (4 KB)

    const int tid  = threadIdx.x;
    const int wv   = __builtin_amdgcn_readfirstlane(tid >> 6);  // wave 0..7 (scalar)
    const int lane = tid & 63;
    const int lane4 = lane * 4;
    const int tok0 = blockIdx.x * 64;
    const int bb   = tok0 >> 12;            // batch index (uniform)
    const int e0   = wv * 8;                // this wave's experts (scalar)

    // per-lane global src for DMA staging: wave wv stages k-chunk wv of each tile
    const float* xrow  = x + (size_t)(tok0 + lane) * DDIM + wv * 4;
    const float* wbase = Wr + (size_t)e0 * WROW;     // scalar; +32 floats per tile

    float acc[8];
    #pragma unroll
    for (int e = 0; e < 8; ++e) acc[e] = wsb[bb * 64 + e0 + e];  // init = task logits

#define STAGE(t) do {                                                         \
        const float* _s = xrow + (t) * 32;                                    \
        float* _d = &xbuf[((t) % 3) * 2048 + wv * 256];                       \
        __builtin_amdgcn_global_load_lds((gp1)_s, (lp3)_d, 16, 0, 0);         \
    } while (0)

#define FMA8(q, W) do {                                                       \
        const float4 xv = *(const float4*)(bufc + (q) * 256 + lane4);         \
        acc[0] += xv.x * (W)[0].x; acc[0] += xv.y * (W)[0].y;                 \
        acc[0] += xv.z * (W)[0].z; acc[0] += xv.w * (W)[0].w;                 \
        acc[1] += xv.x * (W)[1].x; acc[1] += xv.y * (W)[1].y;                 \
        acc[1] += xv.z * (W)[1].z; acc[1] += xv.w * (W)[1].w;                 \
        acc[2] += xv.x * (W)[2].x; acc[2] += xv.y * (W)[2].y;                 \
        acc[2] += xv.z * (W)[2].z; acc[2] += xv.w * (W)[2].w;                 \
        acc[3] += xv.x * (W)[3].x; acc[3] += xv.y * (W)[3].y;                 \
        acc[3] += xv.z * (W)[3].z; acc[3] += xv.w * (W)[3].w;                 \
        acc[4] += xv.x * (W)[4].x; acc[4] += xv.y * (W)[4].y;                 \
        acc[4] += xv.z * (W)[4].z; acc[4] += xv.w * (W)[4].w;                 \
        acc[5] += xv.x * (W)[5].x; acc[5] += xv.y * (W)[5].y;                 \
        acc[5] += xv.z * (W)[5].z; acc[5] += xv.w * (W)[5].w;                 \
        acc[6] += xv.x * (W)[6].x; acc[6] += xv.y * (W)[6].y;                 \
        acc[6] += xv.z * (W)[6].z; acc[6] += xv.w * (W)[6].w;                 \
        acc[7] += xv.x * (W)[7].x; acc[7] += xv.y * (W)[7].y;                 \
        acc[7] += xv.z * (W)[7].z; acc[7] += xv.w * (W)[7].w;                 \
    } while (0)

    // W double-buffer in SGPRs: all indexing compile-time (rule #20)
    f32x4 wA[8], wB[8];
    wload8<0>(wA, wbase);           // subtile (0,0)
    wwait(wA);
    STAGE(0); STAGE(1);

#define TILE_BODY(t) do {                                                     \
        const float* bufc = &xbuf[((t) % 3) * 2048];                          \
        wload8<16>(wB, wbase);  FMA8(0, wA); wwait(wB);                       \
        wload8<32>(wA, wbase);  FMA8(1, wB); wwait(wA);                       \
        wload8<48>(wB, wbase);  FMA8(2, wA); wwait(wB);                       \
        wload8<64>(wA, wbase);  FMA8(3, wB); wwait(wA);                       \
        wload8<80>(wB, wbase);  FMA8(4, wA); wwait(wB);                       \
        wload8<96>(wA, wbase);  FMA8(5, wB); wwait(wA);                       \
        wload8<112>(wB, wbase); FMA8(6, wA); wwait(wB);                       \
        wload8<128>(wA, wbase); FMA8(7, wB); wwait(wA);                       \
        wbase += 32;                        /* next k-tile (128 B) */         \
    } while (0)

    for (int t = 0; t < 62; ++t) {
        asm volatile("s_waitcnt vmcnt(1)" ::: "memory");  // my tile-t DMA landed
        __builtin_amdgcn_s_barrier();                     // all tile-t chunks ready;
                                                          // all waves done with t-1
        STAGE(t + 2);                                     // overwrite slot (t-1)%3
        TILE_BODY(t);
    }
    asm volatile("s_waitcnt vmcnt(1)" ::: "memory");
    __builtin_amdgcn_s_barrier();
    TILE_BODY(62);
    asm volatile("s_waitcnt vmcnt(0)" ::: "memory");
    __builtin_amdgcn_s_barrier();
    TILE_BODY(63);      // q7 W-load reads W[:,2048..2051] (valid row tail, unused)

    // ---- logit exchange: lane=token writes its 8 experts ----
    #pragma unroll
    for (int e = 0; e < 8; e += 4) {
        float4 v; v.x = acc[e]; v.y = acc[e + 1]; v.z = acc[e + 2]; v.w = acc[e + 3];
        *(float4*)&lg[lane * 68 + e0 + e] = v;
    }
    __syncthreads();

    // ---- softmax/top2 for tokens 8wv..8wv+7 ; lane = expert ----
    float pacc = 0.0f, facc = 0.0f;
    for (int i = 0; i < 8; ++i) {
        const int tk = wv * 8 + i;
        const float v = lg[tk * 68 + lane];
        float m1 = v; int i1 = lane;
        #pragma unroll
        for (int off = 32; off; off >>= 1) {
            const float ov = __shfl_xor(m1, off, 64);
            const int   oi = __shfl_xor(i1, off, 64);
            if (ov > m1 || (ov == m1 && oi < i1)) { m1 = ov; i1 = oi; }
        }
        const float vx = (lane == i1) ? -3.4e38f : v;
        float m2 = vx; int i2 = lane;
        #pragma unroll
        for (int off = 32; off; off >>= 1) {
            const float ov = __shfl_xor(m2, off, 64);
            const int   oi = __shfl_xor(i2, off, 64);
            if (ov > m2 || (ov == m2 && oi < i2)) { m2 = ov; i2 = oi; }
        }
        const float p = __expf(v - m1);
        float s = p;
        #pragma unroll
        for (int off = 32; off; off >>= 1) s += __shfl_xor(s, off, 64);
        const float rZ = 1.0f / s;
        const float pn = p * rZ;
        const int   T  = tok0 + tk;
        out[65536 + (size_t)T * 64 + lane] = pn;      // coalesced 256 B
        pacc += pn;
        facc += (lane == i1 ? 1.0f : 0.0f) + (lane == i2 ? 1.0f : 0.0f);
        if (lane == 0) {
            const float q1 = rZ, q2 = __expf(m2 - m1) * rZ;
            const float dn = 1.0f / (q1 + q2 + 1e-8f);
            float2 tw; tw.x = q1 * dn; tw.y = q2 * dn;
            *(float2*)(out + (size_t)T * 2) = tw;
            float2 ti; ti.x = (float)i1; ti.y = (float)i2;
            *(float2*)(out + 32768 + (size_t)T * 2) = ti;
        }
    }

    // ---- block-level P/f reduce -> one atomic per address per block (8 slots) ----
    pf[wv * 128 + lane]      = pacc;
    pf[wv * 128 + 64 + lane] = facc;
    __syncthreads();
    if (wv == 0) {
        float ps = 0.0f, fs = 0.0f;
        #pragma unroll
        for (int w2 = 0; w2 < 8; ++w2) {
            ps += pf[w2 * 128 + lane];
            fs += pf[w2 * 128 + 64 + lane];
        }
        const int slot = blockIdx.x & 7;
        atomicAdd(wsb + 256 + slot * 128 + lane, ps);
        atomicAdd(wsb + 256 + slot * 128 + 64 + lane, fs);
    }
#undef STAGE
#undef FMA8
#undef TILE_BODY
}

// ---------------- kernel 3: aux loss ----------------------------------------------
__global__ void k3_aux(const float* __restrict__ wsb, float* __restrict__ out) {
    const int e = threadIdx.x;  // 64 threads
    float P = 0.0f, F = 0.0f;
    #pragma unroll
    for (int s = 0; s < 8; ++s) {
        P += wsb[256 + s * 128 + e];
        F += wsb[256 + s * 128 + 64 + e];
    }
    float val = P * F;
    #pragma unroll
    for (int off = 32; off; off >>= 1) val += __shfl_xor(val, off, 64);
    if (e == 0)
        out[1114112] = 64.0f * val / (16384.0f * 2.0f * 16384.0f);
}

extern "C" void kernel_launch(void* const* d_in, const int* in_sizes, int n_in,
                              void* d_out, int out_size, void* d_ws, size_t ws_size,
                              hipStream_t stream) {
    (void)in_sizes; (void)n_in; (void)out_size; (void)ws_size;
    const float* x  = (const float*)d_in[0];
    const float* z  = (const float*)d_in[1];
    const float* Wr = (const float*)d_in[2];
    const float* Wp = (const float*)d_in[3];
    const float* bp = (const float*)d_in[4];
    const float* eb = (const float*)d_in[5];
    float* out = (float*)d_out;
    float* wsb = (float*)d_ws;

    hipLaunchKernelGGL(k1_task,  dim3(1),   dim3(256), 0, stream, z, Wp, bp, Wr, eb, wsb);
    hipLaunchKernelGGL(k2_fused, dim3(256), dim3(512), 0, stream, x, Wr, wsb, out);
    hipLaunchKernelGGL(k3_aux,   dim3(1),   dim3(64),  0, stream, wsb, out);
}